// Round 6
// baseline (522.627 us; speedup 1.0000x reference)
//
#include <hip/hip_runtime.h>
#include <hip/hip_bf16.h>

// Problem constants (from setup_inputs): B=4, S=2048, D_IN=2048, D_OUT=2048
constexpr int D_IN  = 2048;
constexpr int D_OUT = 2048;
constexpr int GM = 4 * 2048;      // B*S rows
constexpr int GK = 2 * D_IN;      // 4096 (concat real|imag)
constexpr int GN = 2 * D_OUT;     // 4096 (concat y_real|y_imag channels)

typedef __attribute__((ext_vector_type(8))) short bf16x8;
typedef __attribute__((ext_vector_type(4))) float f32x4;

constexpr int QB = 1024;          // quant unit count

// Exact bf16 bit patterns for {0, +-0.5, +-1}; negate = XOR 0x8000.
__device__ inline unsigned short q4bits(float w) {
    if (w >  0.75f) return 0x3F80;   // 1.0
    if (w >  0.25f) return 0x3F00;   // 0.5
    if (w < -0.75f) return 0xBF80;   // -1.0
    if (w < -0.25f) return 0xBF00;   // -0.5
    return 0;
}

__device__ inline unsigned short bf16b(float x) {
    __hip_bfloat16 h = __float2bfloat16(x);
    unsigned short u;
    __builtin_memcpy(&u, &h, 2);
    return u;
}

// ---------------------------------------------------------------------------
// LN unit: LayerNorm of concat row m (4096 elems) -> A row (bf16).
// ---------------------------------------------------------------------------
__device__ __forceinline__ void ln_unit(int m, int t,
        const float* __restrict__ xr, const float* __restrict__ xi,
        const float* __restrict__ gamma, const float* __restrict__ beta,
        unsigned short* __restrict__ A, float* shf) {
    const float4* r4 = (const float4*)(xr + (size_t)m * D_IN);
    const float4* i4 = (const float4*)(xi + (size_t)m * D_IN);
    float4 vr[2], vi[2];
    float s = 0.f, ss = 0.f;
    for (int c = 0; c < 2; c++) {
        float4 v = r4[t + c * 256];
        vr[c] = v;
        s  += v.x + v.y + v.z + v.w;
        ss += v.x * v.x + v.y * v.y + v.z * v.z + v.w * v.w;
        v = i4[t + c * 256];
        vi[c] = v;
        s  += v.x + v.y + v.z + v.w;
        ss += v.x * v.x + v.y * v.y + v.z * v.z + v.w * v.w;
    }
    for (int off = 32; off; off >>= 1) {
        s  += __shfl_down(s, off, 64);
        ss += __shfl_down(ss, off, 64);
    }
    int lane = t & 63, wv = t >> 6;
    if (lane == 0) { shf[wv] = s; shf[4 + wv] = ss; }
    __syncthreads();
    if (t == 0) {
        float S  = shf[0] + shf[1] + shf[2] + shf[3];
        float SS = shf[4] + shf[5] + shf[6] + shf[7];
        float mu  = S * (1.0f / 4096.0f);
        float var = SS * (1.0f / 4096.0f) - mu * mu;
        shf[8] = mu;
        shf[9] = rsqrtf(var + 1e-6f);
    }
    __syncthreads();
    float mu = shf[8], rs = shf[9];
    const float4* g4 = (const float4*)gamma;
    const float4* b4 = (const float4*)beta;
    ushort4* Arow = (ushort4*)(A + (size_t)m * GK);
    for (int c = 0; c < 2; c++) {
        int k4 = t + c * 256;                 // float4 index in real half
        float4 g = g4[k4], b = b4[k4];
        float4 v = vr[c];
        ushort4 o;
        o.x = bf16b((v.x - mu) * rs * g.x + b.x);
        o.y = bf16b((v.y - mu) * rs * g.y + b.y);
        o.z = bf16b((v.z - mu) * rs * g.z + b.z);
        o.w = bf16b((v.w - mu) * rs * g.w + b.w);
        Arow[k4] = o;
        g = g4[512 + k4]; b = b4[512 + k4];
        v = vi[c];
        o.x = bf16b((v.x - mu) * rs * g.x + b.x);
        o.y = bf16b((v.y - mu) * rs * g.y + b.y);
        o.z = bf16b((v.z - mu) * rs * g.z + b.z);
        o.w = bf16b((v.w - mu) * rs * g.w + b.w);
        Arow[512 + k4] = o;
    }
}

// ---------------------------------------------------------------------------
// Quant unit qb: quantize a 1/QB slab of weights into W_cat + partial sums.
// W_cat row n<2048:  [ qre[n,:] | -qim[n,:] ]   -> y_real channels
// W_cat row n>=2048: [ qim[n,:] |  qre[n,:] ]   -> y_imag channels
// ---------------------------------------------------------------------------
__device__ __forceinline__ void quant_unit(int qb, int t,
        const float* __restrict__ wre, const float* __restrict__ wim,
        unsigned short* __restrict__ wq, float* __restrict__ partial,
        float* shf) {
    float a = 0.f, b = 0.f;
    int tid = qb * 256 + t;                       // 0 .. 262143
    const float4* wre4 = (const float4*)wre;
    const float4* wim4 = (const float4*)wim;
    for (int c = 0; c < 4; c++) {
        int f4i = tid + c * (QB * 256);           // float4 index, coalesced
        int idx = f4i * 4;
        int o = idx >> 11;                        // row in D_OUT
        int k = idx & (D_IN - 1);                 // col in D_IN (mult of 4)
        float4 r = wre4[f4i];
        float4 im = wim4[f4i];
        a += fabsf(r.x) + fabsf(r.y) + fabsf(r.z) + fabsf(r.w);
        b += fabsf(im.x) + fabsf(im.y) + fabsf(im.z) + fabsf(im.w);
        ushort4 qre, qim, nim;
        qre.x = q4bits(r.x);  qre.y = q4bits(r.y);  qre.z = q4bits(r.z);  qre.w = q4bits(r.w);
        qim.x = q4bits(im.x); qim.y = q4bits(im.y); qim.z = q4bits(im.z); qim.w = q4bits(im.w);
        nim.x = qim.x ^ 0x8000; nim.y = qim.y ^ 0x8000;
        nim.z = qim.z ^ 0x8000; nim.w = qim.w ^ 0x8000;
        *(ushort4*)(wq + (size_t)o * GK + k)                  = qre;
        *(ushort4*)(wq + (size_t)o * GK + D_IN + k)           = nim;
        *(ushort4*)(wq + (size_t)(D_OUT + o) * GK + k)        = qim;
        *(ushort4*)(wq + (size_t)(D_OUT + o) * GK + D_IN + k) = qre;
    }
    for (int off = 32; off; off >>= 1) {
        a += __shfl_down(a, off, 64);
        b += __shfl_down(b, off, 64);
    }
    int lane = t & 63, wv = t >> 6;
    if (lane == 0) { shf[wv] = a; shf[4 + wv] = b; }
    __syncthreads();
    if (t == 0) {
        partial[qb]      = shf[0] + shf[1] + shf[2] + shf[3];
        partial[QB + qb] = shf[4] + shf[5] + shf[6] + shf[7];
    }
}

// ---------------------------------------------------------------------------
// Fused prep kernel (grid-split), proven in round 4. Cooperative single-
// dispatch fusion is INCOMPATIBLE with the harness's graph capture (round-5
// correctness failure) -- never again.
// ---------------------------------------------------------------------------
__global__ __launch_bounds__(256) void prep_kernel(
        const float* __restrict__ xr, const float* __restrict__ xi,
        const float* __restrict__ gamma, const float* __restrict__ beta,
        unsigned short* __restrict__ A,
        const float* __restrict__ wre, const float* __restrict__ wim,
        unsigned short* __restrict__ wq, float* __restrict__ partial) {
    __shared__ float shf[10];
    if (blockIdx.x >= GM) {
        quant_unit(blockIdx.x - GM, threadIdx.x, wre, wim, wq, partial, shf);
        return;
    }
    ln_unit(blockIdx.x, threadIdx.x, xr, xi, gamma, beta, A, shf);
}

// ---------------------------------------------------------------------------
// GEMM  Y(GM x GN) = A(GM x GK) * W_cat^T, W_cat stored N x K.
//
// m201 8-phase template, attempt #4 -- the three prior failures are now
// understood and fixed:
//  (1) ds_reads issue BEFORE the phase barrier (drain under barrier skew;
//      r1/r2 read after the barrier -> all waves stalled on lgkmcnt(0)
//      together, serializing LDS-drain with MFMA).
//  (2) staging = half-tile units (128 rows, 2 global_load_lds/thread), one
//      per phase, leading consumption by 4-7 phases.
//  (3) ONE vmcnt(6) per K-tile at phase END (m201's "phases 4 and 8"),
//      covering the NEXT tile's phase-0 ds_reads; 3 units stay in flight.
// In-flight queue (steady, by induction): at tile kt p3 after its stage:
// 7 units = 14 loads -> vmcnt(6) retires the 4 units of tile kt+1 (all
// landed before kt+1 p0's reads), leaves 3 units of kt+2.
//
// Halves match quadrant consumption across the 2Mx4N wave grid:
//   A-half h = rows { p*128 + h*64 .. +63 } (p = wave-row panel)
//   B-half h = rows { q*64 + h*32 .. +31 }  (q = wave-col panel)
// Phase p0 computes Q(0,0) (needs A0,B0), p1 Q(0,1) (B1), p2 Q(1,1) (A1),
// p3 Q(1,0) (regs only). b0/b1 kept in separate registers; a overwritten
// at p2. LDS overwrite safety: kt+2's units (same buffer parity as kt)
// overwrite regions whose reads retired >= 2 barriers earlier.
//
// XOR swizzle (staging pre-swizzled global chunk, reader XOR) and epilogue
// are byte-identical to the correctness-verified r2 kernel.
// ---------------------------------------------------------------------------
__global__ __launch_bounds__(512, 2) void gemm_kernel(
        const unsigned short* __restrict__ A,
        const unsigned short* __restrict__ Wq,
        const float* __restrict__ partial,
        float* __restrict__ out) {
    constexpr int BM = 256, BN = 256, BK = 64;
    constexpr int NT = GK / BK;                  // 64 K-tiles
    __shared__ unsigned short shA[2][BM * BK];   // 2 x 32 KiB
    __shared__ unsigned short shB[2][BN * BK];   // 2 x 32 KiB
    __shared__ float shf[10];

    // XCD-bijective block swizzle (512 blocks, 512 % 8 == 0).
    int lin = blockIdx.y * gridDim.x + blockIdx.x;       // 0..511
    int swz = (lin & 7) * 64 + (lin >> 3);
    int m0 = (swz >> 4) * BM;                            // 32 M-tiles
    int n0 = (swz & 15) * BN;                            // 16 N-tiles

    int t = threadIdx.x;
    int lane = t & 63, wid = t >> 6;         // 8 waves
    int wr = wid >> 2, wc = wid & 3;         // 2 x 4 wave grid
    int quad = lane >> 4, r = lane & 15;
    int srow = lane >> 3;                    // staging: row within 8-row group
    int scol = ((lane & 7) ^ srow) * 8;      // staging: swizzled bf16 col
    int csw0 = (quad ^ (r & 7)) * 8;         // reader: elem offset at ks=0

    int aRow0 = (wr * 128 + r) * BK;         // element offsets into LDS
    int bRow0 = (wc * 64 + r) * BK;

    // Scale-factor prologue (partial[2*QB] is L2-resident, ~2us).
    {
        float a = 0.f, b = 0.f;
        for (int i = t; i < QB; i += 512) { a += partial[i]; b += partial[QB + i]; }
        for (int off = 32; off; off >>= 1) {
            a += __shfl_down(a, off, 64);
            b += __shfl_down(b, off, 64);
        }
        if (lane == 0) { shf[wid] = a; /* 8 waves */ }
        __syncthreads();
        if (lane == 0 && wid == 0) {
            // second operand set: redo for b via shf upper? keep simple:
        }
        // simpler: two-step using 8-slot scratch twice
        __syncthreads();
        if (lane == 0) { shf[wid] = a; }
        __syncthreads();
        if (t == 0) {
            float sa = 0.f; for (int i = 0; i < 8; i++) sa += shf[i];
            shf[8] = sa * (1.0f / (2048.0f * 2048.0f));
        }
        __syncthreads();
        if (lane == 0) { shf[wid] = b; }
        __syncthreads();
        if (t == 0) {
            float sb = 0.f; for (int i = 0; i < 8; i++) sb += shf[i];
            shf[9] = sb * (1.0f / (2048.0f * 2048.0f));
        }
        // visibility covered by the loop's many barriers before epilogue
    }

    f32x4 acc[8][4] = {};
    bf16x8 a[4][2], b0[2][2], b1[2][2];

    // Stage one half-unit (2 global_load_lds per thread), guarded by kk<NT.
#define STAGE_A(bb, kk, h) do {                                                \
        if ((kk) < NT) {                                                       \
            _Pragma("unroll") for (int ss = 0; ss < 2; ++ss) {                 \
                int rowBase = (wid >> 2) * 128 + (h) * 64 + (wid & 3) * 16 + ss * 8; \
                const unsigned short* gp =                                     \
                    A + (size_t)(m0 + rowBase + srow) * GK + (kk) * BK + scol; \
                unsigned short* lp = shA[bb] + rowBase * BK;                   \
                __builtin_amdgcn_global_load_lds(                              \
                    (const __attribute__((address_space(1))) void*)(const void*)gp, \
                    (__attribute__((address_space(3))) void*)(void*)lp, 16, 0, 0);  \
            }                                                                  \
        }                                                                      \
    } while (0)

#define STAGE_B(bb, kk, h) do {                                                \
        if ((kk) < NT) {                                                       \
            _Pragma("unroll") for (int ss = 0; ss < 2; ++ss) {                 \
                int rowBase = (wid >> 1) * 64 + (h) * 32 + (wid & 1) * 16 + ss * 8; \
                const unsigned short* gp =                                     \
                    Wq + (size_t)(n0 + rowBase + srow) * GK + (kk) * BK + scol;\
                unsigned short* lp = shB[bb] + rowBase * BK;                   \
                __builtin_amdgcn_global_load_lds(                              \
                    (const __attribute__((address_space(1))) void*)(const void*)gp, \
                    (__attribute__((address_space(3))) void*)(void*)lp, 16, 0, 0);  \
            }                                                                  \
        }                                                                      \
    } while (0)

#define READ_A(bb, mh) do {                                                    \
        const short* pa_ = (const short*)shA[bb];                              \
        _Pragma("unroll") for (int im = 0; im < 4; ++im)                       \
        _Pragma("unroll") for (int ks = 0; ks < 2; ++ks)                       \
            a[im][ks] = *(const bf16x8*)(pa_ + aRow0                           \
                + ((mh) * 4 + im) * (16 * BK) + (csw0 ^ (ks * 32)));           \
    } while (0)

#define READ_B(bb, nh, dst) do {                                               \
        const short* pb_ = (const short*)shB[bb];                              \
        _Pragma("unroll") for (int jn = 0; jn < 2; ++jn)                       \
        _Pragma("unroll") for (int ks = 0; ks < 2; ++ks)                       \
            dst[jn][ks] = *(const bf16x8*)(pb_ + bRow0                         \
                + ((nh) * 2 + jn) * (16 * BK) + (csw0 ^ (ks * 32)));           \
    } while (0)

#define MFMA_Q(mh, nh, breg) do {                                              \
        __builtin_amdgcn_s_setprio(1);                                         \
        _Pragma("unroll") for (int im = 0; im < 4; ++im)                       \
        _Pragma("unroll") for (int jn = 0; jn < 2; ++jn)                       \
        _Pragma("unroll") for (int ks = 0; ks < 2; ++ks)                       \
            acc[(mh) * 4 + im][(nh) * 2 + jn] =                                \
                __builtin_amdgcn_mfma_f32_16x16x32_bf16(                       \
                    a[im][ks], breg[jn][ks],                                   \
                    acc[(mh) * 4 + im][(nh) * 2 + jn], 0, 0, 0);               \
        __builtin_amdgcn_s_setprio(0);                                         \
    } while (0)

#define WAIT_LGKM0 do {                                                        \
        asm volatile("s_waitcnt lgkmcnt(0)" ::: "memory");                     \
        __builtin_amdgcn_sched_barrier(0);                                     \
    } while (0)

    // Prologue: stage t0:{A0,B0,B1,A1} + t1:{A0,B0,B1}; retire t0 (vmcnt(6)).
    STAGE_A(0, 0, 0); STAGE_B(0, 0, 0); STAGE_B(0, 0, 1); STAGE_A(0, 0, 1);
    STAGE_A(1, 1, 0); STAGE_B(1, 1, 0); STAGE_B(1, 1, 1);
    asm volatile("s_waitcnt vmcnt(6)" ::: "memory");
    __builtin_amdgcn_s_barrier();

    for (int kt = 0; kt < NT; ++kt) {
        int cur = kt & 1, nx1 = cur ^ 1;     // kt+1 -> nx1, kt+2 -> cur

        // ---- p0: Q(0,0) ----
        READ_A(cur, 0);
        READ_B(cur, 0, b0);
        STAGE_A(nx1, kt + 1, 1);             // U(kt+1, A1)
        asm volatile("s_waitcnt lgkmcnt(8)" ::: "memory");
        __builtin_amdgcn_s_barrier();
        WAIT_LGKM0;
        MFMA_Q(0, 0, b0);
        __builtin_amdgcn_s_barrier();

        // ---- p1: Q(0,1) ----
        READ_B(cur, 1, b1);
        STAGE_A(cur, kt + 2, 0);             // U(kt+2, A0)
        __builtin_amdgcn_s_barrier();
        WAIT_LGKM0;
        MFMA_Q(0, 1, b1);
        __builtin_amdgcn_s_barrier();

        // ---- p2: Q(1,1) ----
        READ_A(cur, 1);
        STAGE_B(cur, kt + 2, 0);             // U(kt+2, B0)
        __builtin_amdgcn_s_barrier();
        WAIT_LGKM0;
        MFMA_Q(1, 1, b1);
        __builtin_amdgcn_s_barrier();

        // ---- p3: Q(1,0) (regs only); tile-boundary counted wait ----
        STAGE_B(cur, kt + 2, 1);             // U(kt+2, B1)
        if (kt < NT - 2) asm volatile("s_waitcnt vmcnt(6)" ::: "memory");
        else             asm volatile("s_waitcnt vmcnt(0)" ::: "memory");
        __builtin_amdgcn_s_barrier();
        __builtin_amdgcn_sched_barrier(0);
        MFMA_Q(1, 0, b0);
        __builtin_amdgcn_s_barrier();
    }

#undef STAGE_A
#undef STAGE_B
#undef READ_A
#undef READ_B
#undef MFMA_Q
#undef WAIT_LGKM0

    // Epilogue (verified in r2): per-block uniform half selection.
    float scale;
    float* obase;
    int ncol0;
    if (n0 < D_OUT) { scale = shf[8]; obase = out;                      ncol0 = n0; }
    else            { scale = shf[9]; obase = out + (size_t)GM * D_OUT; ncol0 = n0 - D_OUT; }

    #pragma unroll
    for (int f = 0; f < 8; ++f)
        #pragma unroll
        for (int g = 0; g < 4; ++g) {
            int mrow = m0 + wr * 128 + f * 16 + quad * 4;  // row=(lane>>4)*4+reg
            int ncol = ncol0 + wc * 64 + g * 16 + r;       // col=lane&15
            #pragma unroll
            for (int reg = 0; reg < 4; ++reg)
                obase[(size_t)(mrow + reg) * D_OUT + ncol] = acc[f][g][reg] * scale;
        }
}

extern "C" void kernel_launch(void* const* d_in, const int* in_sizes, int n_in,
                              void* d_out, int out_size, void* d_ws, size_t ws_size,
                              hipStream_t stream) {
    const float* xr    = (const float*)d_in[0];
    const float* xi    = (const float*)d_in[1];
    const float* wre   = (const float*)d_in[2];
    const float* wim   = (const float*)d_in[3];
    const float* gamma = (const float*)d_in[4];
    const float* beta  = (const float*)d_in[5];
    float* out = (float*)d_out;

    // ws layout: A bf16 (GM*GK), W_cat bf16 (GN*GK), partial (2*QB f32)
    unsigned short* A  = (unsigned short*)d_ws;
    unsigned short* Wq = (unsigned short*)((char*)d_ws + (size_t)GM * GK * 2);
    float* partial = (float*)((char*)d_ws + (size_t)GM * GK * 2 + (size_t)GN * GK * 2);

    prep_kernel<<<GM + QB, 256, 0, stream>>>(xr, xi, gamma, beta, A,
                                             wre, wim, Wq, partial);
    gemm_kernel<<<dim3(GN / 256, GM / 256), 512, 0, stream>>>(A, Wq, partial, out);
}

// Round 7
// 472.479 us; speedup vs baseline: 1.1061x; 1.1061x over previous
//
#include <hip/hip_runtime.h>
#include <hip/hip_bf16.h>

// Problem constants (from setup_inputs): B=4, S=2048, D_IN=2048, D_OUT=2048
constexpr int D_IN  = 2048;
constexpr int D_OUT = 2048;
constexpr int GM = 4 * 2048;      // B*S rows
constexpr int GK = 2 * D_IN;      // 4096 (concat real|imag)
constexpr int GN = 2 * D_OUT;     // 4096 (concat y_real|y_imag channels)

typedef __attribute__((ext_vector_type(8))) short bf16x8;
typedef __attribute__((ext_vector_type(4))) float f32x4;

constexpr int QB = 1024;          // quant unit count

// Exact bf16 bit patterns for {0, +-0.5, +-1}; negate = XOR 0x8000.
__device__ inline unsigned short q4bits(float w) {
    if (w >  0.75f) return 0x3F80;   // 1.0
    if (w >  0.25f) return 0x3F00;   // 0.5
    if (w < -0.75f) return 0xBF80;   // -1.0
    if (w < -0.25f) return 0xBF00;   // -0.5
    return 0;
}

__device__ inline unsigned short bf16b(float x) {
    __hip_bfloat16 h = __float2bfloat16(x);
    unsigned short u;
    __builtin_memcpy(&u, &h, 2);
    return u;
}

// ---------------------------------------------------------------------------
// LN unit: LayerNorm of concat row m (4096 elems) -> A row (bf16).
// Verified in rounds 4/6.
// ---------------------------------------------------------------------------
__device__ __forceinline__ void ln_unit(int m, int t,
        const float* __restrict__ xr, const float* __restrict__ xi,
        const float* __restrict__ gamma, const float* __restrict__ beta,
        unsigned short* __restrict__ A, float* shf) {
    const float4* r4 = (const float4*)(xr + (size_t)m * D_IN);
    const float4* i4 = (const float4*)(xi + (size_t)m * D_IN);
    float4 vr[2], vi[2];
    float s = 0.f, ss = 0.f;
    for (int c = 0; c < 2; c++) {
        float4 v = r4[t + c * 256];
        vr[c] = v;
        s  += v.x + v.y + v.z + v.w;
        ss += v.x * v.x + v.y * v.y + v.z * v.z + v.w * v.w;
        v = i4[t + c * 256];
        vi[c] = v;
        s  += v.x + v.y + v.z + v.w;
        ss += v.x * v.x + v.y * v.y + v.z * v.z + v.w * v.w;
    }
    for (int off = 32; off; off >>= 1) {
        s  += __shfl_down(s, off, 64);
        ss += __shfl_down(ss, off, 64);
    }
    int lane = t & 63, wv = t >> 6;
    if (lane == 0) { shf[wv] = s; shf[4 + wv] = ss; }
    __syncthreads();
    if (t == 0) {
        float S  = shf[0] + shf[1] + shf[2] + shf[3];
        float SS = shf[4] + shf[5] + shf[6] + shf[7];
        float mu  = S * (1.0f / 4096.0f);
        float var = SS * (1.0f / 4096.0f) - mu * mu;
        shf[8] = mu;
        shf[9] = rsqrtf(var + 1e-6f);
    }
    __syncthreads();
    float mu = shf[8], rs = shf[9];
    const float4* g4 = (const float4*)gamma;
    const float4* b4 = (const float4*)beta;
    ushort4* Arow = (ushort4*)(A + (size_t)m * GK);
    for (int c = 0; c < 2; c++) {
        int k4 = t + c * 256;                 // float4 index in real half
        float4 g = g4[k4], b = b4[k4];
        float4 v = vr[c];
        ushort4 o;
        o.x = bf16b((v.x - mu) * rs * g.x + b.x);
        o.y = bf16b((v.y - mu) * rs * g.y + b.y);
        o.z = bf16b((v.z - mu) * rs * g.z + b.z);
        o.w = bf16b((v.w - mu) * rs * g.w + b.w);
        Arow[k4] = o;
        g = g4[512 + k4]; b = b4[512 + k4];
        v = vi[c];
        o.x = bf16b((v.x - mu) * rs * g.x + b.x);
        o.y = bf16b((v.y - mu) * rs * g.y + b.y);
        o.z = bf16b((v.z - mu) * rs * g.z + b.z);
        o.w = bf16b((v.w - mu) * rs * g.w + b.w);
        Arow[512 + k4] = o;
    }
}

// ---------------------------------------------------------------------------
// Quant unit qb: quantize a 1/QB slab of weights into W_cat + partial sums.
// W_cat row n<2048:  [ qre[n,:] | -qim[n,:] ]   -> y_real channels
// W_cat row n>=2048: [ qim[n,:] |  qre[n,:] ]   -> y_imag channels
// Verified in rounds 4/6.
// ---------------------------------------------------------------------------
__device__ __forceinline__ void quant_unit(int qb, int t,
        const float* __restrict__ wre, const float* __restrict__ wim,
        unsigned short* __restrict__ wq, float* __restrict__ partial,
        float* shf) {
    float a = 0.f, b = 0.f;
    int tid = qb * 256 + t;                       // 0 .. 262143
    const float4* wre4 = (const float4*)wre;
    const float4* wim4 = (const float4*)wim;
    for (int c = 0; c < 4; c++) {
        int f4i = tid + c * (QB * 256);           // float4 index, coalesced
        int idx = f4i * 4;
        int o = idx >> 11;                        // row in D_OUT
        int k = idx & (D_IN - 1);                 // col in D_IN (mult of 4)
        float4 r = wre4[f4i];
        float4 im = wim4[f4i];
        a += fabsf(r.x) + fabsf(r.y) + fabsf(r.z) + fabsf(r.w);
        b += fabsf(im.x) + fabsf(im.y) + fabsf(im.z) + fabsf(im.w);
        ushort4 qre, qim, nim;
        qre.x = q4bits(r.x);  qre.y = q4bits(r.y);  qre.z = q4bits(r.z);  qre.w = q4bits(r.w);
        qim.x = q4bits(im.x); qim.y = q4bits(im.y); qim.z = q4bits(im.z); qim.w = q4bits(im.w);
        nim.x = qim.x ^ 0x8000; nim.y = qim.y ^ 0x8000;
        nim.z = qim.z ^ 0x8000; nim.w = qim.w ^ 0x8000;
        *(ushort4*)(wq + (size_t)o * GK + k)                  = qre;
        *(ushort4*)(wq + (size_t)o * GK + D_IN + k)           = nim;
        *(ushort4*)(wq + (size_t)(D_OUT + o) * GK + k)        = qim;
        *(ushort4*)(wq + (size_t)(D_OUT + o) * GK + D_IN + k) = qre;
    }
    for (int off = 32; off; off >>= 1) {
        a += __shfl_down(a, off, 64);
        b += __shfl_down(b, off, 64);
    }
    int lane = t & 63, wv = t >> 6;
    if (lane == 0) { shf[wv] = a; shf[4 + wv] = b; }
    __syncthreads();
    if (t == 0) {
        partial[qb]      = shf[0] + shf[1] + shf[2] + shf[3];
        partial[QB + qb] = shf[4] + shf[5] + shf[6] + shf[7];
    }
}

// ---------------------------------------------------------------------------
// Fused prep kernel (grid-split), verified round 4. Cooperative single-
// dispatch fusion is INCOMPATIBLE with harness graph capture (round-5
// failure) -- never again.
// ---------------------------------------------------------------------------
__global__ __launch_bounds__(256) void prep_kernel(
        const float* __restrict__ xr, const float* __restrict__ xi,
        const float* __restrict__ gamma, const float* __restrict__ beta,
        unsigned short* __restrict__ A,
        const float* __restrict__ wre, const float* __restrict__ wim,
        unsigned short* __restrict__ wq, float* __restrict__ partial) {
    __shared__ float shf[10];
    if (blockIdx.x >= GM) {
        quant_unit(blockIdx.x - GM, threadIdx.x, wre, wim, wq, partial, shf);
        return;
    }
    ln_unit(blockIdx.x, threadIdx.x, xr, xi, gamma, beta, A, shf);
}

// ---------------------------------------------------------------------------
// GEMM  Y(GM x GN) = A(GM x GK) * W_cat^T, W_cat stored N x K.
//
// SCHEDULE = the verified round-0 loop, untouched: single-buffered LDS,
// stage -> __syncthreads -> 2x(ds_read frags + MFMA) -> __syncthreads.
// Four schedule rewrites (r1,r2,r3,r6: 35-42% MfmaUtil) all lost to this
// structure's 54%; the schedule is closed.
//
// TILING change only (the lever the CU arithmetic says is real):
//   block 256x128, 4 waves in 2x2, per-wave output 128x64 (acc[8][4]).
//   Wave-tile area 64x64 -> 128x64 raises LDS fragment reuse from
//   32 -> 43.7 FLOP per LDS-byte (-27% ds_read traffic per FLOP) and cuts
//   staged bytes per FLOP by 25% (48 KB LDS per 4.2 MFLOP-tile vs
//   32 KB per 2.1 MFLOP). Round-0's near-co-critical LDS-vs-MFMA balance
//   (why schedule changes never paid) flips to MFMA-dominant.
//   Cost: ~220 regs/wave -> 8 waves/CU (occupancy 38->25%); r3 showed
//   8 waves/CU sustains >=42% even with a worse schedule.
// Staging pattern, BK=64, XOR swizzle (stage chunk (lane&7)^(lane>>3),
// reader chunk ^ (r&7)) identical to round-0; fragment-indexing family
// (wr*128 + f*16 + r) correctness-proven in r1/r2/r6.
// ---------------------------------------------------------------------------
__global__ __launch_bounds__(256, 2) void gemm_kernel(
        const unsigned short* __restrict__ A,
        const unsigned short* __restrict__ Wq,
        const float* __restrict__ partial,
        float* __restrict__ out) {
    constexpr int BM = 256, BN = 128, BK = 64;
    __shared__ unsigned short lsA[BM * BK];   // 32 KiB
    __shared__ unsigned short lsB[BN * BK];   // 16 KiB
    __shared__ float shf[10];
    int n0 = blockIdx.x * BN;                 // 32 N-blocks
    int m0 = blockIdx.y * BM;                 // 32 M-blocks
    int t = threadIdx.x, lane = t & 63, wave = t >> 6;
    int wr = wave >> 1, wc = wave & 1;        // 2x2 wave grid
    int quad = lane >> 4, r = lane & 15;
    int srow = lane >> 3;                     // staging: row within 8-row group
    int scol = ((lane & 7) ^ srow) * 8;       // staging: swizzled bf16 col
    int csw0 = ((quad ^ (r & 7)) * 8);        // reader: elem offset, ks=0

    // Prologue: reduce partial sums -> scale factors (once per block, cheap,
    // overlaps the first tile's staging latency). Verified round 4.
    {
        float a = 0.f, b = 0.f;
        for (int i = t; i < QB; i += 256) { a += partial[i]; b += partial[QB + i]; }
        for (int off = 32; off; off >>= 1) {
            a += __shfl_down(a, off, 64);
            b += __shfl_down(b, off, 64);
        }
        if (lane == 0) { shf[wave] = a; shf[4 + wave] = b; }
        __syncthreads();
        if (t == 0) {
            shf[8] = (shf[0] + shf[1] + shf[2] + shf[3]) * (1.0f / (2048.0f * 2048.0f));
            shf[9] = (shf[4] + shf[5] + shf[6] + shf[7]) * (1.0f / (2048.0f * 2048.0f));
        }
        // visibility covered by the K-loop's __syncthreads before epilogue
    }

    f32x4 acc[8][4] = {};

    for (int k0 = 0; k0 < GK; k0 += BK) {
        // stage A tile (256 rows x 64 cols bf16): 8 issues of 16B per thread
        for (int i = 0; i < 8; i++) {
            int row = i * 32 + wave * 8;
            const unsigned short* gp = A + (size_t)(m0 + row + srow) * GK + k0 + scol;
            unsigned short* lp = lsA + row * BK;   // wave-uniform LDS base
            __builtin_amdgcn_global_load_lds(
                (const __attribute__((address_space(1))) void*)(const void*)gp,
                (__attribute__((address_space(3))) void*)(void*)lp, 16, 0, 0);
        }
        // stage W tile (128 rows x 64 cols bf16): 4 issues
        for (int i = 0; i < 4; i++) {
            int row = i * 32 + wave * 8;
            const unsigned short* gp = Wq + (size_t)(n0 + row + srow) * GK + k0 + scol;
            unsigned short* lp = lsB + row * BK;
            __builtin_amdgcn_global_load_lds(
                (const __attribute__((address_space(1))) void*)(const void*)gp,
                (__attribute__((address_space(3))) void*)(void*)lp, 16, 0, 0);
        }
        __syncthreads();
        for (int ks = 0; ks < 2; ks++) {
            bf16x8 af[8], bfr[4];
            const short* pa = (const short*)lsA;
            const short* pb = (const short*)lsB;
            int coff = csw0 ^ (ks * 32);
            #pragma unroll
            for (int f = 0; f < 8; f++)
                af[f] = *(const bf16x8*)(pa + (wr * 128 + f * 16 + r) * BK + coff);
            #pragma unroll
            for (int g = 0; g < 4; g++)
                bfr[g] = *(const bf16x8*)(pb + (wc * 64 + g * 16 + r) * BK + coff);
            #pragma unroll
            for (int f = 0; f < 8; f++)
                #pragma unroll
                for (int g = 0; g < 4; g++)
                    acc[f][g] = __builtin_amdgcn_mfma_f32_16x16x32_bf16(
                        af[f], bfr[g], acc[f][g], 0, 0, 0);
        }
        __syncthreads();
    }

    // Epilogue: per-block uniform half selection (BN=128 divides D_OUT)
    float scale;
    float* obase;
    int ncol0;
    if (n0 < D_OUT) { scale = shf[8]; obase = out;                      ncol0 = n0; }
    else            { scale = shf[9]; obase = out + (size_t)GM * D_OUT; ncol0 = n0 - D_OUT; }

    #pragma unroll
    for (int f = 0; f < 8; f++)
        #pragma unroll
        for (int g = 0; g < 4; g++) {
            int mrow = m0 + wr * 128 + f * 16 + quad * 4;  // row=(lane>>4)*4+reg
            int ncol = ncol0 + wc * 64 + g * 16 + r;       // col=lane&15
            #pragma unroll
            for (int reg = 0; reg < 4; reg++)
                obase[(size_t)(mrow + reg) * D_OUT + ncol] = acc[f][g][reg] * scale;
        }
}

extern "C" void kernel_launch(void* const* d_in, const int* in_sizes, int n_in,
                              void* d_out, int out_size, void* d_ws, size_t ws_size,
                              hipStream_t stream) {
    const float* xr    = (const float*)d_in[0];
    const float* xi    = (const float*)d_in[1];
    const float* wre   = (const float*)d_in[2];
    const float* wim   = (const float*)d_in[3];
    const float* gamma = (const float*)d_in[4];
    const float* beta  = (const float*)d_in[5];
    float* out = (float*)d_out;

    // ws layout: A bf16 (GM*GK), W_cat bf16 (GN*GK), partial (2*QB f32)
    unsigned short* A  = (unsigned short*)d_ws;
    unsigned short* Wq = (unsigned short*)((char*)d_ws + (size_t)GM * GK * 2);
    float* partial = (float*)((char*)d_ws + (size_t)GM * GK * 2 + (size_t)GN * GK * 2);

    prep_kernel<<<GM + QB, 256, 0, stream>>>(xr, xi, gamma, beta, A,
                                             wre, wim, Wq, partial);
    gemm_kernel<<<dim3(GN / 128, GM / 256), 256, 0, stream>>>(A, Wq, partial, out);
}